// Round 1
// baseline (278.389 us; speedup 1.0000x reference)
//
#include <hip/hip_runtime.h>
#include <math.h>

// Problem constants (reference: B=4, S=4096, D=2048, E=64, K=2)
#define NTOK   16384            // B*S
#define DDIM   2048
#define NEXP   64
#define HALF_K 1024             // K-split of 2 over DDIM
#define PSTRIDE (NTOK * NEXP)   // 1048576 floats per output tensor

// ---------------------------------------------------------------------------
// Kernel 1: partial logits GEMM.
//   grid = 512 blocks: 256 token tiles (BM=64) x K-split 2.
//   Each block computes partial[ksp][tok0..tok0+63][0..63] over its K half
//   and writes it to d_out (masks region = partial0, probs region = partial1).
//   Every element of d_out is written (harness re-poisons to 0xAA).
// ---------------------------------------------------------------------------
__global__ __launch_bounds__(256) void gemm_partial_kernel(
    const float* __restrict__ x, const float* __restrict__ W,
    float* __restrict__ out)
{
    // LDS tiles, row stride 20 floats (=80B, 16B-aligned rows, breaks pow2 banks)
    __shared__ float xs[64 * 20];
    __shared__ float ws[64 * 20];

    const int tid  = threadIdx.x;
    const int tile = blockIdx.x >> 1;
    const int ksp  = blockIdx.x & 1;
    const int m0   = tile * 64;
    const int k0   = ksp * HALF_K;

    const int ty = tid >> 4;   // 0..15 -> tokens  ty*4 .. ty*4+3
    const int tx = tid & 15;   // 0..15 -> experts tx*4 .. tx*4+3

    float acc[4][4];
#pragma unroll
    for (int i = 0; i < 4; ++i)
#pragma unroll
        for (int j = 0; j < 4; ++j) acc[i][j] = 0.f;

    const int srow = tid >> 2;        // 0..63
    const int sc4  = (tid & 3) * 4;   // 0,4,8,12

    for (int kb = 0; kb < HALF_K; kb += 16) {
        // stage x tile 64x16 and W tile 64x16 (one float4 per thread each)
        float4 xv = *(const float4*)&x[(size_t)(m0 + srow) * DDIM + (k0 + kb + sc4)];
        float4 wv = *(const float4*)&W[(size_t)srow * DDIM + (k0 + kb + sc4)];
        __syncthreads();   // previous iteration's readers done before overwrite
        *(float4*)&xs[srow * 20 + sc4] = xv;
        *(float4*)&ws[srow * 20 + sc4] = wv;
        __syncthreads();

#pragma unroll
        for (int kk = 0; kk < 16; kk += 4) {
            float4 a[4], b[4];
#pragma unroll
            for (int i = 0; i < 4; ++i) a[i] = *(const float4*)&xs[(ty * 4 + i) * 20 + kk];
#pragma unroll
            for (int j = 0; j < 4; ++j) b[j] = *(const float4*)&ws[(tx * 4 + j) * 20 + kk];
#pragma unroll
            for (int i = 0; i < 4; ++i)
#pragma unroll
                for (int j = 0; j < 4; ++j) {
                    acc[i][j] += a[i].x * b[j].x;
                    acc[i][j] += a[i].y * b[j].y;
                    acc[i][j] += a[i].z * b[j].z;
                    acc[i][j] += a[i].w * b[j].w;
                }
        }
    }

    float* dst = out + (size_t)ksp * PSTRIDE;
#pragma unroll
    for (int i = 0; i < 4; ++i) {
        const int tok = m0 + ty * 4 + i;
#pragma unroll
        for (int j = 0; j < 4; ++j)
            dst[(size_t)tok * NEXP + (tx * 4 + j)] = acc[i][j];
    }
}

// ---------------------------------------------------------------------------
// Kernel 2: epilogue. One 64-lane wave per token, lane = expert.
//   logits = partial0 + partial1 + bias; softmax; top-2 (stable, lower index
//   wins ties, selected on probs to match lax.top_k(probs)); in-place write:
//   masks -> region 0, probs -> region 1.
// ---------------------------------------------------------------------------
__global__ __launch_bounds__(256) void router_epilogue(
    float* out, const float* __restrict__ bias)
{
    const int tid  = threadIdx.x;
    const int e    = tid & 63;
    const int t    = blockIdx.x * 4 + (tid >> 6);

    const size_t o0 = (size_t)t * NEXP + e;
    float l = out[o0] + out[PSTRIDE + o0] + bias[e];

    // wave max
    float m = l;
#pragma unroll
    for (int off = 32; off > 0; off >>= 1)
        m = fmaxf(m, __shfl_xor(m, off));

    float ex = __expf(l - m);
    float s = ex;
#pragma unroll
    for (int off = 32; off > 0; off >>= 1)
        s += __shfl_xor(s, off);
    float p = ex / s;

    // top-1 on probs (tie -> lower index)
    float v = p; int idx = e;
#pragma unroll
    for (int off = 32; off > 0; off >>= 1) {
        float v2 = __shfl_xor(v, off);
        int   i2 = __shfl_xor(idx, off);
        if (v2 > v || (v2 == v && i2 < idx)) { v = v2; idx = i2; }
    }
    const int e1 = idx;

    // top-2: exclude e1 (p >= 0, so -1 is a safe sentinel)
    v = (e == e1) ? -1.0f : p; idx = e;
#pragma unroll
    for (int off = 32; off > 0; off >>= 1) {
        float v2 = __shfl_xor(v, off);
        int   i2 = __shfl_xor(idx, off);
        if (v2 > v || (v2 == v && i2 < idx)) { v = v2; idx = i2; }
    }
    const int e2 = idx;

    out[o0]           = (e == e1 || e == e2) ? 1.0f : 0.0f;
    out[PSTRIDE + o0] = p;
}

extern "C" void kernel_launch(void* const* d_in, const int* in_sizes, int n_in,
                              void* d_out, int out_size, void* d_ws, size_t ws_size,
                              hipStream_t stream) {
    const float* x = (const float*)d_in[0];   // [4,4096,2048] f32
    const float* W = (const float*)d_in[1];   // [64,2048] f32
    const float* b = (const float*)d_in[2];   // [64] f32
    (void)in_sizes; (void)n_in; (void)d_ws; (void)ws_size; (void)out_size;
    float* out = (float*)d_out;               // [masks | probs], each 1048576 f32

    hipLaunchKernelGGL(gemm_partial_kernel, dim3(512), dim3(256), 0, stream, x, W, out);
    hipLaunchKernelGGL(router_epilogue, dim3(NTOK / 4), dim3(256), 0, stream, out, b);
}

// Round 2
// 271.632 us; speedup vs baseline: 1.0249x; 1.0249x over previous
//
#include <hip/hip_runtime.h>
#include <math.h>

// B=4, S=4096, D=2048, E=64, K=2
#define NTOK    16384
#define DDIM    2048
#define NEXP    64
#define PSTRIDE (NTOK * NEXP)
#define WELEMS  (NEXP * DDIM)      // 131072

typedef _Float16 half8  __attribute__((ext_vector_type(8)));
typedef float    floatx4 __attribute__((ext_vector_type(4)));

// ---------------------------------------------------------------------------
// Precompute: W (fp32) -> W_hi (fp16) + W_lo (fp16, scaled by 2^11).
// hi*hi products are exact in fp32; lo terms restore ~22 mantissa bits.
// ---------------------------------------------------------------------------
__global__ __launch_bounds__(256) void wconv_kernel(
    const float* __restrict__ W, _Float16* __restrict__ wh, _Float16* __restrict__ wl)
{
    int i = blockIdx.x * 256 + threadIdx.x;          // grid 512*256 == WELEMS
    float w = W[i];
    _Float16 h = (_Float16)w;
    wh[i] = h;
    wl[i] = (_Float16)((w - (float)h) * 2048.0f);    // scale keeps lo in normal range
}

// ---------------------------------------------------------------------------
// Fused router: GEMM (fp16-split MFMA) + softmax + top-2, no LDS, no barriers.
// 256 blocks x 4 waves; wave = 16 tokens x 64 experts.
// ---------------------------------------------------------------------------
__global__ __launch_bounds__(256) void router_kernel(
    const float* __restrict__ x,
    const _Float16* __restrict__ wh,
    const _Float16* __restrict__ wl,
    const float* __restrict__ bias,
    float* __restrict__ out)
{
    const int lane = threadIdx.x & 63;
    const int wid  = threadIdx.x >> 6;
    const int t0   = blockIdx.x * 64 + wid * 16;   // wave's token base
    const int mrow = lane & 15;                    // A-frag token row / B-frag expert col
    const int quad = lane >> 4;                    // k sub-chunk
    const int koff = quad * 8;

    floatx4 acc_hh[4], acc_md[4];
#pragma unroll
    for (int j = 0; j < 4; ++j) {
        acc_hh[j] = (floatx4)0.0f;
        acc_md[j] = (floatx4)0.0f;
    }

    const float* xrow = x + (size_t)(t0 + mrow) * DDIM + koff;
    const _Float16* whp[4];
    const _Float16* wlp[4];
#pragma unroll
    for (int j = 0; j < 4; ++j) {
        whp[j] = wh + (size_t)(j * 16 + mrow) * DDIM + koff;
        wlp[j] = wl + (size_t)(j * 16 + mrow) * DDIM + koff;
    }

#pragma unroll 2
    for (int k = 0; k < DDIM; k += 32) {
        // A fragment: 8 fp32 -> hi/lo fp16
        floatx4 v0 = *(const floatx4*)(xrow + k);
        floatx4 v1 = *(const floatx4*)(xrow + k + 4);
        half8 a_hi, a_lo;
#pragma unroll
        for (int i = 0; i < 4; ++i) {
            float f = v0[i];
            _Float16 h = (_Float16)f;
            a_hi[i] = h;
            a_lo[i] = (_Float16)((f - (float)h) * 2048.0f);
        }
#pragma unroll
        for (int i = 0; i < 4; ++i) {
            float f = v1[i];
            _Float16 h = (_Float16)f;
            a_hi[4 + i] = h;
            a_lo[4 + i] = (_Float16)((f - (float)h) * 2048.0f);
        }

#pragma unroll
        for (int j = 0; j < 4; ++j) {
            half8 bh = *(const half8*)(whp[j] + k);
            half8 bl = *(const half8*)(wlp[j] + k);
            acc_hh[j] = __builtin_amdgcn_mfma_f32_16x16x32_f16(a_hi, bh, acc_hh[j], 0, 0, 0);
            acc_md[j] = __builtin_amdgcn_mfma_f32_16x16x32_f16(a_hi, bl, acc_md[j], 0, 0, 0);
            acc_md[j] = __builtin_amdgcn_mfma_f32_16x16x32_f16(a_lo, bh, acc_md[j], 0, 0, 0);
        }
    }

    // ---- epilogue: lane owns tokens t0 + quad*4 + r (r=0..3), experts 16j+c ----
    const int c = mrow;
    float bj[4];
#pragma unroll
    for (int j = 0; j < 4; ++j) bj[j] = bias[j * 16 + c];

    float logit[4][4];   // [j][r]
#pragma unroll
    for (int j = 0; j < 4; ++j)
#pragma unroll
        for (int r = 0; r < 4; ++r)
            logit[j][r] = acc_hh[j][r] + acc_md[j][r] * (1.0f / 2048.0f) + bj[j];

#pragma unroll
    for (int r = 0; r < 4; ++r) {
        const int trow = t0 + quad * 4 + r;

        // softmax over 64 experts (4 local j x 16 lanes of this quad)
        float m = logit[0][r];
#pragma unroll
        for (int j = 1; j < 4; ++j) m = fmaxf(m, logit[j][r]);
#pragma unroll
        for (int off = 1; off <= 8; off <<= 1) m = fmaxf(m, __shfl_xor(m, off));

        float pj[4], s = 0.0f;
#pragma unroll
        for (int j = 0; j < 4; ++j) { pj[j] = __expf(logit[j][r] - m); s += pj[j]; }
#pragma unroll
        for (int off = 1; off <= 8; off <<= 1) s += __shfl_xor(s, off);
        const float rinv = 1.0f / s;

        // stable top-2 on logits (tie -> lower expert index)
        float v1 = -1e30f, v2 = -1e30f; int i1 = -1, i2 = -1;
#pragma unroll
        for (int j = 0; j < 4; ++j) {
            float v = logit[j][r]; int e = j * 16 + c;
            if (v > v1 || (v == v1 && e < i1)) { v2 = v1; i2 = i1; v1 = v; i1 = e; }
            else if (v > v2 || (v == v2 && e < i2)) { v2 = v; i2 = e; }
        }
#pragma unroll
        for (int off = 1; off <= 8; off <<= 1) {
            float u1 = __shfl_xor(v1, off); int k1 = __shfl_xor(i1, off);
            float u2 = __shfl_xor(v2, off); int k2 = __shfl_xor(i2, off);
            if (u1 > v1 || (u1 == v1 && k1 < i1)) {
                if (v1 > u2 || (v1 == u2 && i1 < k2)) { v2 = v1; i2 = i1; }
                else                                   { v2 = u2; i2 = k2; }
                v1 = u1; i1 = k1;
            } else {
                if (u1 > v2 || (u1 == v2 && k1 < i2)) { v2 = u1; i2 = k1; }
            }
        }

        // write masks (region 0) and probs (region 1)
#pragma unroll
        for (int j = 0; j < 4; ++j) {
            const int col = j * 16 + c;
            const size_t o = (size_t)trow * NEXP + col;
            out[o]           = (col == i1 || col == i2) ? 1.0f : 0.0f;
            out[PSTRIDE + o] = pj[j] * rinv;
        }
    }
}

extern "C" void kernel_launch(void* const* d_in, const int* in_sizes, int n_in,
                              void* d_out, int out_size, void* d_ws, size_t ws_size,
                              hipStream_t stream) {
    const float* x = (const float*)d_in[0];   // [4,4096,2048]
    const float* W = (const float*)d_in[1];   // [64,2048]
    const float* b = (const float*)d_in[2];   // [64]
    (void)in_sizes; (void)n_in; (void)out_size; (void)ws_size;
    float* out = (float*)d_out;

    _Float16* wh = (_Float16*)d_ws;           // 131072 fp16
    _Float16* wl = wh + WELEMS;               // 131072 fp16 (scaled lo)

    hipLaunchKernelGGL(wconv_kernel, dim3(WELEMS / 256), dim3(256), 0, stream, W, wh, wl);
    hipLaunchKernelGGL(router_kernel, dim3(NTOK / 64), dim3(256), 0, stream, x, wh, wl, b, out);
}

// Round 3
// 254.144 us; speedup vs baseline: 1.0954x; 1.0688x over previous
//
#include <hip/hip_runtime.h>
#include <math.h>

// B=4, S=4096, D=2048, E=64, K=2
#define NTOK    16384
#define DDIM    2048
#define NEXP    64
#define PSTRIDE (NTOK * NEXP)
#define WELEMS  (NEXP * DDIM)      // 131072
#define KSLICE  512                // DDIM / 4 waves

typedef _Float16 half8   __attribute__((ext_vector_type(8)));
typedef float    floatx4 __attribute__((ext_vector_type(4)));

// ---------------------------------------------------------------------------
// W (fp32) -> W_hi (fp16) + W_lo (fp16, residual scaled by 2^11).
// ---------------------------------------------------------------------------
__global__ __launch_bounds__(256) void wconv_kernel(
    const float* __restrict__ W, _Float16* __restrict__ wh, _Float16* __restrict__ wl)
{
    int i = blockIdx.x * 256 + threadIdx.x;          // grid 512*256 == WELEMS
    float w = W[i];
    _Float16 h = (_Float16)w;
    wh[i] = h;
    wl[i] = (_Float16)((w - (float)h) * 2048.0f);
}

// ---------------------------------------------------------------------------
// Fused router, K-split x4 per block.
//   Block = 16 tokens, 4 waves; wave w covers k in [512w, 512w+512).
//   Grid = 1024 blocks -> 4 blocks/CU, 16 waves/CU.
//   LDS all-reduce of partial accumulators; wave 0 does softmax + top-2.
// ---------------------------------------------------------------------------
__global__ __launch_bounds__(256, 4) void router_kernel(
    const float* __restrict__ x,
    const _Float16* __restrict__ wh,
    const _Float16* __restrict__ wl,
    const float* __restrict__ bias,
    float* __restrict__ out)
{
    __shared__ float red[3][32][64];   // [srcwave-1][frag][lane], conflict-free

    const int lane = threadIdx.x & 63;
    const int wid  = threadIdx.x >> 6;
    const int t0   = blockIdx.x * 16;
    const int mrow = lane & 15;        // A token row / B expert col
    const int quad = lane >> 4;
    const int koff = quad * 8;
    const int k0   = wid * KSLICE;

    floatx4 acc_hh[4], acc_md[4];
#pragma unroll
    for (int j = 0; j < 4; ++j) { acc_hh[j] = (floatx4)0.0f; acc_md[j] = (floatx4)0.0f; }

    const float*    xrow = x  + (size_t)(t0 + mrow) * DDIM + k0 + koff;
    const _Float16* whb  = wh + (size_t)mrow * DDIM + k0 + koff;
    const _Float16* wlb  = wl + (size_t)mrow * DDIM + k0 + koff;

    // 1-ahead prefetch of the HBM-latency x chunk
    floatx4 nv0 = *(const floatx4*)(xrow);
    floatx4 nv1 = *(const floatx4*)(xrow + 4);

#pragma unroll 4
    for (int k = 0; k < KSLICE; k += 32) {
        floatx4 v0 = nv0, v1 = nv1;
        if (k + 32 < KSLICE) {
            nv0 = *(const floatx4*)(xrow + k + 32);
            nv1 = *(const floatx4*)(xrow + k + 36);
        }

        half8 a_hi, a_lo;
#pragma unroll
        for (int i = 0; i < 4; ++i) {
            float f = v0[i];
            _Float16 h = (_Float16)f;
            a_hi[i] = h;
            a_lo[i] = (_Float16)((f - (float)h) * 2048.0f);
        }
#pragma unroll
        for (int i = 0; i < 4; ++i) {
            float f = v1[i];
            _Float16 h = (_Float16)f;
            a_hi[4 + i] = h;
            a_lo[4 + i] = (_Float16)((f - (float)h) * 2048.0f);
        }

#pragma unroll
        for (int j = 0; j < 4; ++j) {
            half8 bh = *(const half8*)(whb + (size_t)j * 16 * DDIM + k);
            half8 bl = *(const half8*)(wlb + (size_t)j * 16 * DDIM + k);
            acc_hh[j] = __builtin_amdgcn_mfma_f32_16x16x32_f16(a_hi, bh, acc_hh[j], 0, 0, 0);
            acc_md[j] = __builtin_amdgcn_mfma_f32_16x16x32_f16(a_hi, bl, acc_md[j], 0, 0, 0);
            acc_md[j] = __builtin_amdgcn_mfma_f32_16x16x32_f16(a_lo, bh, acc_md[j], 0, 0, 0);
        }
    }

    // ---- cross-wave K reduction through LDS ----
    if (wid > 0) {
#pragma unroll
        for (int j = 0; j < 4; ++j)
#pragma unroll
            for (int r = 0; r < 4; ++r) {
                red[wid - 1][j * 4 + r][lane]      = acc_hh[j][r];
                red[wid - 1][16 + j * 4 + r][lane] = acc_md[j][r];
            }
    }
    __syncthreads();
    if (wid != 0) return;

#pragma unroll
    for (int w = 0; w < 3; ++w)
#pragma unroll
        for (int j = 0; j < 4; ++j)
#pragma unroll
            for (int r = 0; r < 4; ++r) {
                acc_hh[j][r] += red[w][j * 4 + r][lane];
                acc_md[j][r] += red[w][16 + j * 4 + r][lane];
            }

    // ---- epilogue: lane owns tokens t0 + quad*4 + r, experts 16j + mrow ----
    const int c = mrow;
    float bj[4];
#pragma unroll
    for (int j = 0; j < 4; ++j) bj[j] = bias[j * 16 + c];

    float logit[4][4];
#pragma unroll
    for (int j = 0; j < 4; ++j)
#pragma unroll
        for (int r = 0; r < 4; ++r)
            logit[j][r] = acc_hh[j][r] + acc_md[j][r] * (1.0f / 2048.0f) + bj[j];

#pragma unroll
    for (int r = 0; r < 4; ++r) {
        const int trow = t0 + quad * 4 + r;

        float m = logit[0][r];
#pragma unroll
        for (int j = 1; j < 4; ++j) m = fmaxf(m, logit[j][r]);
#pragma unroll
        for (int off = 1; off <= 8; off <<= 1) m = fmaxf(m, __shfl_xor(m, off));

        float pj[4], s = 0.0f;
#pragma unroll
        for (int j = 0; j < 4; ++j) { pj[j] = __expf(logit[j][r] - m); s += pj[j]; }
#pragma unroll
        for (int off = 1; off <= 8; off <<= 1) s += __shfl_xor(s, off);
        const float rinv = 1.0f / s;

        // stable top-2 on logits (tie -> lower expert index)
        float v1 = -1e30f, v2 = -1e30f; int i1 = -1, i2 = -1;
#pragma unroll
        for (int j = 0; j < 4; ++j) {
            float v = logit[j][r]; int e = j * 16 + c;
            if (v > v1 || (v == v1 && e < i1)) { v2 = v1; i2 = i1; v1 = v; i1 = e; }
            else if (v > v2 || (v == v2 && e < i2)) { v2 = v; i2 = e; }
        }
#pragma unroll
        for (int off = 1; off <= 8; off <<= 1) {
            float u1 = __shfl_xor(v1, off); int q1 = __shfl_xor(i1, off);
            float u2 = __shfl_xor(v2, off); int q2 = __shfl_xor(i2, off);
            if (u1 > v1 || (u1 == v1 && q1 < i1)) {
                if (v1 > u2 || (v1 == u2 && i1 < q2)) { v2 = v1; i2 = i1; }
                else                                   { v2 = u2; i2 = q2; }
                v1 = u1; i1 = q1;
            } else {
                if (u1 > v2 || (u1 == v2 && q1 < i2)) { v2 = u1; i2 = q1; }
            }
        }

#pragma unroll
        for (int j = 0; j < 4; ++j) {
            const int col = j * 16 + c;
            const size_t o = (size_t)trow * NEXP + col;
            out[o]           = (col == i1 || col == i2) ? 1.0f : 0.0f;
            out[PSTRIDE + o] = pj[j] * rinv;
        }
    }
}

extern "C" void kernel_launch(void* const* d_in, const int* in_sizes, int n_in,
                              void* d_out, int out_size, void* d_ws, size_t ws_size,
                              hipStream_t stream) {
    const float* x = (const float*)d_in[0];
    const float* W = (const float*)d_in[1];
    const float* b = (const float*)d_in[2];
    (void)in_sizes; (void)n_in; (void)out_size; (void)ws_size;
    float* out = (float*)d_out;

    _Float16* wh = (_Float16*)d_ws;           // 131072 fp16
    _Float16* wl = wh + WELEMS;               // 131072 fp16

    hipLaunchKernelGGL(wconv_kernel, dim3(WELEMS / 256), dim3(256), 0, stream, W, wh, wl);
    hipLaunchKernelGGL(router_kernel, dim3(NTOK / 16), dim3(256), 0, stream, x, wh, wl, b, out);
}

// Round 4
// 233.054 us; speedup vs baseline: 1.1945x; 1.0905x over previous
//
#include <hip/hip_runtime.h>
#include <math.h>

// B=4, S=4096, D=2048, E=64, K=2
#define NTOK    16384
#define DDIM    2048
#define NEXP    64
#define PSTRIDE (NTOK * NEXP)
#define KP      512              // k per phase
#define PHASES  (DDIM / KP)      // 4
#define ROWP    (KP + 8)         // padded LDS row stride (fp16): breaks bank aliasing
#define HOFF    (NEXP * ROWP)    // lo-plane offset in LDS fp16 elems

typedef _Float16 half8   __attribute__((ext_vector_type(8)));
typedef _Float16 half4   __attribute__((ext_vector_type(4)));
typedef float    floatx4 __attribute__((ext_vector_type(4)));

// ---------------------------------------------------------------------------
// Single fused kernel. Block = 64 tokens (4 waves x 16 tokens), full K.
// Per phase: stage W fp32 -> (hi, lo*2^11) fp16 into padded LDS, then a
// 16-step MFMA loop whose ONLY vmem traffic is the coalesced x stream
// (B-frags come from LDS on the lgkmcnt counter -> x pipelines freely).
// Accumulate across phases in registers; wave-local softmax + top-2 epilogue.
// ---------------------------------------------------------------------------
__global__ __launch_bounds__(256) void router_kernel(
    const float* __restrict__ x,
    const float* __restrict__ W,
    const float* __restrict__ bias,
    float* __restrict__ out)
{
    __shared__ _Float16 wlds[2 * NEXP * ROWP];   // 133,120 B -> 1 block/CU

    const int tid  = threadIdx.x;
    const int lane = tid & 63;
    const int wid  = tid >> 6;
    const int t0   = blockIdx.x * 64;
    const int mrow = lane & 15;      // A token row / B expert col
    const int quad = lane >> 4;      // k sub-offset quad*8

    // bias for this lane's 4 expert columns (constant across phases)
    float bj[4];
#pragma unroll
    for (int j = 0; j < 4; ++j) bj[j] = bias[j * 16 + mrow];

    floatx4 acc_hh[4], acc_md[4];
#pragma unroll
    for (int j = 0; j < 4; ++j) { acc_hh[j] = (floatx4)0.0f; acc_md[j] = (floatx4)0.0f; }

    const float* xrow = x + (size_t)(t0 + wid * 16 + mrow) * DDIM + quad * 8;
    const _Float16* wh_frag = &wlds[mrow * ROWP + quad * 8];

    for (int p = 0; p < PHASES; ++p) {
        const int k0 = p * KP;

        __syncthreads();   // all waves done reading previous slice

        // ---- stage W[:, k0:k0+512] as hi/lo fp16 into padded LDS ----
        // 64 experts x 512 k = 32768 floats = 256 thr x 32 floats (8 float4)
#pragma unroll 8
        for (int i = 0; i < 32; ++i) {
            const int f  = tid + (i << 8);        // 0..8191 float4-chunks
            const int e  = f >> 7;                // 128 chunks per expert row
            const int kc = (f & 127) << 2;
            floatx4 w4 = *(const floatx4*)&W[(size_t)e * DDIM + k0 + kc];
            half4 h4, l4;
#pragma unroll
            for (int c = 0; c < 4; ++c) {
                float wv = w4[c];
                _Float16 h = (_Float16)wv;
                h4[c] = h;
                l4[c] = (_Float16)((wv - (float)h) * 2048.0f);
            }
            *((half4*)&wlds[e * ROWP + kc])        = h4;
            *((half4*)&wlds[HOFF + e * ROWP + kc]) = l4;
        }

        __syncthreads();   // slice visible to all waves

        // ---- 16 MFMA steps over this 512-k slice; vmcnt queue = x only ----
        const float* xp = xrow + k0;
#pragma unroll
        for (int s = 0; s < 16; ++s) {
            floatx4 v0 = *(const floatx4*)(xp + s * 32);
            floatx4 v1 = *(const floatx4*)(xp + s * 32 + 4);

            half8 a_hi, a_lo;
#pragma unroll
            for (int i = 0; i < 4; ++i) {
                float fv = v0[i];
                _Float16 h = (_Float16)fv;
                a_hi[i] = h;
                a_lo[i] = (_Float16)((fv - (float)h) * 2048.0f);
            }
#pragma unroll
            for (int i = 0; i < 4; ++i) {
                float fv = v1[i];
                _Float16 h = (_Float16)fv;
                a_hi[4 + i] = h;
                a_lo[4 + i] = (_Float16)((fv - (float)h) * 2048.0f);
            }

#pragma unroll
            for (int j = 0; j < 4; ++j) {
                const int ro = j * 16 * ROWP + s * 32;
                half8 bh = *(const half8*)(wh_frag + ro);
                half8 bl = *(const half8*)(wh_frag + HOFF + ro);
                acc_hh[j] = __builtin_amdgcn_mfma_f32_16x16x32_f16(a_hi, bh, acc_hh[j], 0, 0, 0);
                acc_md[j] = __builtin_amdgcn_mfma_f32_16x16x32_f16(a_hi, bl, acc_md[j], 0, 0, 0);
                acc_md[j] = __builtin_amdgcn_mfma_f32_16x16x32_f16(a_lo, bh, acc_md[j], 0, 0, 0);
            }
        }
    }

    // ---- wave-local epilogue: lane owns tokens t0+wid*16+quad*4+r,
    //      experts j*16 + mrow ----
    const int c = mrow;
    float logit[4][4];
#pragma unroll
    for (int j = 0; j < 4; ++j)
#pragma unroll
        for (int r = 0; r < 4; ++r)
            logit[j][r] = acc_hh[j][r] + acc_md[j][r] * (1.0f / 2048.0f) + bj[j];

#pragma unroll
    for (int r = 0; r < 4; ++r) {
        const int trow = t0 + wid * 16 + quad * 4 + r;

        float m = logit[0][r];
#pragma unroll
        for (int j = 1; j < 4; ++j) m = fmaxf(m, logit[j][r]);
#pragma unroll
        for (int off = 1; off <= 8; off <<= 1) m = fmaxf(m, __shfl_xor(m, off));

        float pj[4], s = 0.0f;
#pragma unroll
        for (int j = 0; j < 4; ++j) { pj[j] = __expf(logit[j][r] - m); s += pj[j]; }
#pragma unroll
        for (int off = 1; off <= 8; off <<= 1) s += __shfl_xor(s, off);
        const float rinv = 1.0f / s;

        // stable top-2 on logits (tie -> lower expert index)
        float v1 = -1e30f, v2 = -1e30f; int i1 = -1, i2 = -1;
#pragma unroll
        for (int j = 0; j < 4; ++j) {
            float v = logit[j][r]; int e = j * 16 + c;
            if (v > v1 || (v == v1 && e < i1)) { v2 = v1; i2 = i1; v1 = v; i1 = e; }
            else if (v > v2 || (v == v2 && e < i2)) { v2 = v; i2 = e; }
        }
#pragma unroll
        for (int off = 1; off <= 8; off <<= 1) {
            float u1 = __shfl_xor(v1, off); int q1 = __shfl_xor(i1, off);
            float u2 = __shfl_xor(v2, off); int q2 = __shfl_xor(i2, off);
            if (u1 > v1 || (u1 == v1 && q1 < i1)) {
                if (v1 > u2 || (v1 == u2 && i1 < q2)) { v2 = v1; i2 = i1; }
                else                                   { v2 = u2; i2 = q2; }
                v1 = u1; i1 = q1;
            } else {
                if (u1 > v2 || (u1 == v2 && q1 < i2)) { v2 = u1; i2 = q1; }
            }
        }

#pragma unroll
        for (int j = 0; j < 4; ++j) {
            const int col = j * 16 + c;
            const size_t o = (size_t)trow * NEXP + col;
            out[o]           = (col == i1 || col == i2) ? 1.0f : 0.0f;
            out[PSTRIDE + o] = pj[j] * rinv;
        }
    }
}

extern "C" void kernel_launch(void* const* d_in, const int* in_sizes, int n_in,
                              void* d_out, int out_size, void* d_ws, size_t ws_size,
                              hipStream_t stream) {
    const float* x = (const float*)d_in[0];   // [4,4096,2048] f32
    const float* W = (const float*)d_in[1];   // [64,2048] f32
    const float* b = (const float*)d_in[2];   // [64] f32
    (void)in_sizes; (void)n_in; (void)out_size; (void)d_ws; (void)ws_size;
    float* out = (float*)d_out;               // [masks | probs]

    hipLaunchKernelGGL(router_kernel, dim3(NTOK / 64), dim3(256), 0, stream, x, W, b, out);
}